// Round 18
// baseline (127.126 us; speedup 1.0000x reference)
//
#include <hip/hip_runtime.h>

typedef _Float16 f16;
typedef __attribute__((ext_vector_type(8))) _Float16 f16x8;
typedef __attribute__((ext_vector_type(4))) _Float16 f16x4;
typedef __attribute__((ext_vector_type(4))) float f32x4;

#define MFMA16(a, b, c) __builtin_amdgcn_mfma_f32_16x16x32_f16(a, b, c, 0, 0, 0)

#define B_N 16384
#define E_N 9
#define MAXT 144
#define MP_MAX 17536

#define D_IN 512
#define D_H1 512
#define D_H2 256
#define D_H3 128
#define D_A 16

// ---- shared ws header ----
#define IDX_I 64
// pipeline layout (Path A)
#define SIDX_B 65792
#define XG_B 136192
#define H1_B 18093056
#define H2_B 136192
#define H3_B 9114624
#define WS_NEED_PIPE 36049920ull
// fused layout (Path B, round-13 proven)
#define F_RPW 104
#define F_O4B 7667712
#define F_WPL 7704576
#define F_WSLOTS (F_WPL / 16)
#define F_WP_OFF 131584
#define F_H2_OFF 32768
#define F_RING_OFF 49152
#define F_LDS 73728
#define F_NTILE 520

// Path A tile-blocked layout: chunk = (slot>>7)*(W/64) + (k>>6), 16KB each:
// [r=slot&127][128B]; phys byte p holds logical kbyte p ^ ((r&7)<<4).
// NOTE: swizzle is 3-bit (&7): rows are 128B, (r&15)<<4 would overflow (R17 bug).

// ---------------- common helpers ----------------

__device__ __forceinline__ void dma16(const char* g, char* l) {
  __builtin_amdgcn_global_load_lds(
      (const __attribute__((address_space(1))) void*)g,
      (__attribute__((address_space(3))) void*)l, 16, 0, 0);
}

template <int N> __device__ __forceinline__ void waitv();
template <> __device__ __forceinline__ void waitv<2>() {
  asm volatile("s_waitcnt vmcnt(2)" ::: "memory");
}
template <> __device__ __forceinline__ void waitv<1>() {
  asm volatile("s_waitcnt vmcnt(1)" ::: "memory");
}
template <> __device__ __forceinline__ void waitv<0>() {
  asm volatile("s_waitcnt vmcnt(0)" ::: "memory");
}

// ---------------- bucketing (extended: cnt/uoff/pof/ptil + scatter) ----------------

__global__ void k_bucket(const int* __restrict__ pos, int* __restrict__ hdr,
                         int* __restrict__ idx) {
  __shared__ int cnt[E_N], cur[E_N];
  __shared__ int flag_s;
  const int t = threadIdx.x;  // 1024
  if (t < E_N) cnt[t] = 0;
  if (t == 0) {
    int nz = 0;
    for (int i = 0; i < 64; ++i) nz |= pos[2 * i + 1];
    flag_s = (nz == 0) ? 1 : 0;
  }
  __syncthreads();
  const bool f64 = flag_s != 0;
  int e[16];
#pragma unroll
  for (int k = 0; k < 16; ++k) {
    int i = k * 1024 + t;
    long long v = f64 ? ((const long long*)pos)[i] : (long long)pos[i];
    v = v < 0 ? 0 : (v > 8 ? 8 : v);
    e[k] = (int)v;
    atomicAdd(&cnt[e[k]], 1);
  }
  __syncthreads();
  if (t == 0) {
    int ua = 0, pa = 0, ta = 0;
    for (int ee = 0; ee < E_N; ++ee) {
      cur[ee] = ua;
      hdr[8 + ee] = cnt[ee];
      hdr[20 + ee] = ua;
      hdr[32 + ee] = pa;
      hdr[44 + ee] = ta;
      int c = cnt[ee];
      ua += c;
      int tl = (c + 127) >> 7;
      pa += tl << 7;
      ta += tl;
    }
    hdr[32 + 9] = pa;
    hdr[44 + 9] = ta;
  }
  __syncthreads();
#pragma unroll
  for (int k = 0; k < 16; ++k) {
    int i = k * 1024 + t;
    int slot = atomicAdd(&cur[e[k]], 1);
    idx[slot] = i;
  }
}

// ================= Path A: decomposed pipeline =================

__global__ void k_xcvt(const float* __restrict__ x, const int* __restrict__ hdr,
                       const int* __restrict__ idx, char* __restrict__ xg,
                       int* __restrict__ sidx) {
  const int* cnt = hdr + 8;
  const int* uoff = hdr + 20;
  const int* pof = hdr + 32;
  const int Mp = pof[9];
  int gtid = blockIdx.x * 256 + threadIdx.x;

  if (gtid < MP_MAX) {
    int v = -1;
    if (gtid < Mp) {
      int e = 0;
#pragma unroll
      for (int ee = 1; ee < E_N; ++ee) if (gtid >= pof[ee]) e = ee;
      int i = gtid - pof[e];
      if (i < cnt[e]) v = idx[uoff[e] + i];
    }
    sidx[gtid] = v;
  }

  if (gtid >= Mp * 64) return;
  long L = (long)gtid << 4;
  int c = (int)(L >> 14);
  int tile = c >> 3, ks = c & 7;
  int r = (int)((L >> 7) & 127);
  int pos = (int)(L & 127);
  int slot = (tile << 7) + r;
  int klog = pos ^ ((r & 7) << 4);   // 3-bit swizzle: stays within 128B row
  int k = (ks << 6) + (klog >> 1);

  int e = 0;
#pragma unroll
  for (int ee = 1; ee < E_N; ++ee) if (slot >= pof[ee]) e = ee;
  int i = slot - pof[e];
  f16x8 h;
  if (i < cnt[e]) {
    int orig = idx[uoff[e] + i];
    const float* src = x + (long)orig * D_IN + k;
    float4 a = *(const float4*)src;
    float4 b = *(const float4*)(src + 4);
    h[0] = (f16)a.x; h[1] = (f16)a.y; h[2] = (f16)a.z; h[3] = (f16)a.w;
    h[4] = (f16)b.x; h[5] = (f16)b.y; h[6] = (f16)b.z; h[7] = (f16)b.w;
  } else {
#pragma unroll
    for (int q = 0; q < 8; ++q) h[q] = (f16)0.f;
  }
  *(f16x8*)(xg + L) = h;
}

__device__ __forceinline__ f16x8 afragP(const char* base, int rowoff, int kbytes,
                                        int lane) {
  int m = rowoff + (lane & 15);
  int q = kbytes + ((lane >> 4) * 16);
  return *(const f16x8*)(base + m * 128 + (q ^ ((m & 7) << 4)));
}

template <int K, int NTN>
__launch_bounds__(512, 2)
__global__ void k_gemm(const char* __restrict__ Ag, const float* __restrict__ W,
                       const float* __restrict__ bias, const int* __restrict__ hdr,
                       char* __restrict__ Og) {
  constexpr int NOUT = NTN * 128;
  constexpr int S = K / 64;
  constexpr int OCH = NOUT / 64;
  __shared__ __align__(16) char lds[65536];

  const int* pof = hdr + 32;
  const int* ptil = hdr + 44;
  int nb = blockIdx.x;
  int tb = nb / NTN, nt = nb % NTN;
  if (tb >= ptil[9]) return;
  int e = 0;
#pragma unroll
  for (int ee = 1; ee < E_N; ++ee) if (tb >= ptil[ee]) e = ee;
  const int slot0 = pof[e] + (tb - ptil[e]) * 128;

  const int t = threadIdx.x;
  const int lane = t & 63;
  const int wid = t >> 6;
  const int lg = lane >> 4;
  const int ln = lane & 15;
  const int mw = wid >> 1;
  const int nw = wid & 1;

  const char* Abase = Ag + (((long)(slot0 >> 7) * S) << 14);

  auto stageA = [&](int s, int p) {
    const char* src = Abase + ((long)s << 14) + wid * 1024 + lane * 16;
    char* d0 = lds + p * 16384 + wid * 1024;
    dma16(src, d0);
    dma16(src + 8192, d0 + 8192);
  };
  auto stageW = [&](int s, int p) {
    char* wd = lds + 32768 + p * 16384;
#pragma unroll
    for (int j = 0; j < 2; ++j) {
      int q = t + j * 512;
      int col = q >> 3, kb16 = q & 7;
      int klog = (kb16 * 16) ^ ((col & 7) << 4);   // 3-bit swizzle
      int k = s * 64 + (klog >> 1);
      const float* wsrc = W + ((long)(e * NOUT + nt * 128 + col) * K + k);
      float4 a = *(const float4*)wsrc;
      float4 b = *(const float4*)(wsrc + 4);
      f16x8 h;
      h[0] = (f16)a.x; h[1] = (f16)a.y; h[2] = (f16)a.z; h[3] = (f16)a.w;
      h[4] = (f16)b.x; h[5] = (f16)b.y; h[6] = (f16)b.z; h[7] = (f16)b.w;
      *(f16x8*)(wd + q * 16) = h;
    }
  };

  f32x4 acc[2][4];
#pragma unroll
  for (int m2 = 0; m2 < 2; ++m2)
#pragma unroll
    for (int nf = 0; nf < 4; ++nf) acc[m2][nf] = (f32x4){0.f, 0.f, 0.f, 0.f};

  stageA(0, 0);
  stageW(0, 0);
  __syncthreads();

  for (int s = 0; s < S; ++s) {
    const int p = s & 1;
    if (s + 1 < S) { stageA(s + 1, p ^ 1); stageW(s + 1, p ^ 1); }
    const char* Ap = lds + p * 16384;
    const char* Wp = lds + 32768 + p * 16384;
#pragma unroll
    for (int ks = 0; ks < 2; ++ks) {
      f16x8 A0 = afragP(Ap, mw * 32, ks * 64, lane);
      f16x8 A1 = afragP(Ap, mw * 32 + 16, ks * 64, lane);
#pragma unroll
      for (int nf = 0; nf < 4; ++nf) {
        f16x8 B = afragP(Wp, nw * 64 + nf * 16, ks * 64, lane);
        acc[0][nf] = MFMA16(A0, B, acc[0][nf]);
        acc[1][nf] = MFMA16(A1, B, acc[1][nf]);
      }
    }
    __syncthreads();
  }

#pragma unroll
  for (int nf = 0; nf < 4; ++nf) {
    int cg = nt * 128 + nw * 64 + nf * 16 + ln;
    float bb = bias[e * NOUT + cg];
#pragma unroll
    for (int m2 = 0; m2 < 2; ++m2)
#pragma unroll
      for (int j = 0; j < 4; ++j) {
        float v = acc[m2][nf][j] + bb;
        v = v > 0.f ? v : 0.f;
        int row = mw * 32 + m2 * 16 + lg * 4 + j;
        int slot = slot0 + row;
        long byte = ((long)((slot >> 7) * OCH + (cg >> 6)) << 14) +
                    (long)(slot & 127) * 128 +
                    (((cg & 63) * 2) ^ ((slot & 7) << 4));   // 3-bit swizzle
        *(f16*)(Og + byte) = (f16)v;
      }
  }
}

__global__ void k_l4(const char* __restrict__ h3, const float* __restrict__ W4,
                     const float* __restrict__ b4, const int* __restrict__ hdr,
                     const int* __restrict__ sidx, float* __restrict__ out) {
  const int* pof = hdr + 32;
  const int* ptil = hdr + 44;
  int tb = blockIdx.x;
  if (tb >= ptil[9]) return;
  int e = 0;
#pragma unroll
  for (int ee = 1; ee < E_N; ++ee) if (tb >= ptil[ee]) e = ee;
  const int slot0 = pof[e] + (tb - ptil[e]) * 128;

  const int t = threadIdx.x;  // 256
  const int rr = t >> 4, a = t & 15;
#pragma unroll
  for (int g = 0; g < 8; ++g) {
    int slot = slot0 + g * 16 + rr;
    float accv = b4[e * D_A + a];
#pragma unroll
    for (int c = 0; c < 16; ++c) {
      long byte = ((long)((slot >> 7) * 2 + (c >> 3)) << 14) +
                  (long)(slot & 127) * 128 +
                  (((c & 7) * 16) ^ ((slot & 7) << 4));   // 3-bit swizzle
      f16x8 h = *(const f16x8*)(h3 + byte);
      const float* w = W4 + ((long)(e * D_A + a) * D_H3 + c * 8);
      float4 wa = *(const float4*)w;
      float4 wb = *(const float4*)(w + 4);
      accv += (float)h[0] * wa.x + (float)h[1] * wa.y + (float)h[2] * wa.z +
              (float)h[3] * wa.w + (float)h[4] * wb.x + (float)h[5] * wb.y +
              (float)h[6] * wb.z + (float)h[7] * wb.w;
    }
    float mx = accv;
    for (int msk = 8; msk >= 1; msk >>= 1) mx = fmaxf(mx, __shfl_xor(mx, msk, 16));
    float pe = expf(accv - mx);
    float sm = pe;
    for (int msk = 8; msk >= 1; msk >>= 1) sm += __shfl_xor(sm, msk, 16);
    int orig = sidx[slot];
    if (orig >= 0) out[(long)orig * D_A + a] = pe / sm;
  }
}

// ================= Path B: round-13 fused kernel (proven) =================

__global__ void k_wcvt_f(const float* __restrict__ W1, const float* __restrict__ W2,
                         const float* __restrict__ W3, const float* __restrict__ W4,
                         char* __restrict__ wp) {
  int slot = blockIdx.x * 256 + threadIdx.x;
  if (slot >= F_WSLOTS) return;
  long addr = (long)slot << 4;
  int lane = slot & 63;
  int lg = lane >> 4, ln = lane & 15;
  const float* src;
  if (addr < F_O4B) {
    int rec = (int)(addr >> 10);
    int f = rec % F_RPW;
    int ew = rec / F_RPW;
    int w = ew & 7, e = ew >> 3;
    if (f < 64) {
      int kk = f >> 2, nf = f & 3;
      int n = w * 64 + nf * 16 + ln;
      int k = kk * 32 + lg * 8;
      src = W1 + ((long)e * D_H1 + n) * D_IN + k;
    } else if (f < 96) {
      int j = f - 64;
      int kk = j >> 1, nf = j & 1;
      int n = w * 32 + nf * 16 + ln;
      int k = kk * 32 + lg * 8;
      src = W2 + ((long)e * D_H2 + n) * D_H1 + k;
    } else {
      int kk = f - 96;
      int n = w * 16 + ln;
      int k = kk * 32 + lg * 8;
      src = W3 + ((long)e * D_H3 + n) * D_H2 + k;
    }
  } else {
    long rel = addr - F_O4B;
    int e = (int)(rel >> 12);
    int r2 = (int)(rel & 4095);
    int s = r2 >> 4, n = s >> 4, k16 = s & 15;
    src = W4 + ((long)e * D_A + n) * D_H3 + k16 * 8;
  }
  float4 a = *(const float4*)src;
  float4 b = *(const float4*)(src + 4);
  f16x8 h;
  h[0] = (f16)a.x; h[1] = (f16)a.y; h[2] = (f16)a.z; h[3] = (f16)a.w;
  h[4] = (f16)b.x; h[5] = (f16)b.y; h[6] = (f16)b.z; h[7] = (f16)b.w;
  *(f16x8*)(wp + addr) = h;
}

__device__ __forceinline__ f16x8 afragS(const char* base, int strideB, int rowoff,
                                        int kbytes, int lane) {
  int m = rowoff + (lane & 15);
  int q = kbytes + ((lane >> 4) * 16);
  return *(const f16x8*)(base + m * strideB + (q ^ ((m & 15) << 4)));
}

__launch_bounds__(512, 2)
__global__ void k_mlp_f(const float* __restrict__ x,
                        const float* __restrict__ b1, const float* __restrict__ b2,
                        const float* __restrict__ b3, const float* __restrict__ b4,
                        const int* __restrict__ hdr, const int* __restrict__ idx,
                        const char* __restrict__ wp, float* __restrict__ out) {
  __shared__ __align__(16) char lds[F_LDS];

  int b = blockIdx.x;
  int bswz = (b & 7) * (F_NTILE / 8) + (b >> 3);

  const int* counts = hdr + 8;
  int e = -1, tile = 0, base = 0, ne = 0;
  {
    int acc = 0, off = 0;
    for (int ee = 0; ee < E_N; ++ee) {
      int n = counts[ee];
      int nt = (n + 31) / 32;
      if (bswz < acc + nt) { e = ee; tile = bswz - acc; ne = n; base = off; break; }
      acc += nt; off += n;
    }
  }
  if (e < 0) return;
  const int rvalid = min(32, ne - tile * 32);
  const int row0 = base + tile * 32;

  const int t = threadIdx.x;
  const int lane = t & 63;
  const int wid = t >> 6;
  const int lg = lane >> 4;
  const int ln = lane & 15;

  const char* wb = wp + ((long)(e * 8 + wid) * F_RPW << 10);
  const char* wpe4 = wp + F_O4B + (long)e * 4096;
  char* ringw = lds + F_RING_OFF + wid * 3072;

  dma16(wb + 0 * 1024 + lane * 16, ringw + 0 * 1024);
  dma16(wb + 1 * 1024 + lane * 16, ringw + 1 * 1024);
  dma16(wb + 2 * 1024 + lane * 16, ringw + 2 * 1024);

  const float4* x4 = (const float4*)x;
#pragma unroll
  for (int v8 = 0; v8 < 8; ++v8) {
    int u = v8 * 512 + t;
    int s = u >> 7, c4 = u & 127;
    float4 v = make_float4(0.f, 0.f, 0.f, 0.f);
    if (s < rvalid) v = x4[(long)idx[row0 + s] * (D_IN / 4) + c4];
    f16x4 h;
    h[0] = (f16)v.x; h[1] = (f16)v.y; h[2] = (f16)v.z; h[3] = (f16)v.w;
    *(f16x4*)(lds + s * 1024 + ((c4 * 8) ^ ((s & 15) << 4))) = h;
  }
  __syncthreads();

  {
    f32x4 acc[2][4];
#pragma unroll
    for (int m = 0; m < 2; ++m)
#pragma unroll
      for (int nf = 0; nf < 4; ++nf) acc[m][nf] = (f32x4){0.f, 0.f, 0.f, 0.f};

#pragma unroll
    for (int kk = 0; kk < 16; ++kk) {
      f16x8 A0 = afragS(lds, 1024, 0, kk * 64, lane);
      f16x8 A1 = afragS(lds, 1024, 16, kk * 64, lane);
#pragma unroll
      for (int nf = 0; nf < 4; ++nf) {
        const int rec = kk * 4 + nf;
        waitv<2>();
        f16x8 B = *(const f16x8*)(ringw + (rec % 3) * 1024 + lane * 16);
        __builtin_amdgcn_s_setprio(1);
        acc[0][nf] = MFMA16(A0, B, acc[0][nf]);
        acc[1][nf] = MFMA16(A1, B, acc[1][nf]);
        __builtin_amdgcn_s_setprio(0);
        const int nr = rec + 3;
        dma16(wb + (long)nr * 1024 + lane * 16, ringw + (nr % 3) * 1024);
      }
    }
    __syncthreads();

#pragma unroll
    for (int nf = 0; nf < 4; ++nf) {
      int n = wid * 64 + nf * 16 + ln;
      float bias = b1[e * D_H1 + n];
#pragma unroll
      for (int m = 0; m < 2; ++m)
#pragma unroll
        for (int j = 0; j < 4; ++j) {
          float v = acc[m][nf][j] + bias;
          v = v > 0.f ? v : 0.f;
          int rw = m * 16 + lg * 4 + j;
          *(f16*)(lds + rw * 1024 + ((n * 2) ^ ((rw & 15) << 4))) = (f16)v;
        }
    }
  }
  __syncthreads();

  {
    f32x4 acc2[2][2];
#pragma unroll
    for (int m = 0; m < 2; ++m)
#pragma unroll
      for (int nf = 0; nf < 2; ++nf) acc2[m][nf] = (f32x4){0.f, 0.f, 0.f, 0.f};

#pragma unroll
    for (int kk = 0; kk < 16; ++kk) {
      f16x8 A0 = afragS(lds, 1024, 0, kk * 64, lane);
      f16x8 A1 = afragS(lds, 1024, 16, kk * 64, lane);
#pragma unroll
      for (int nf = 0; nf < 2; ++nf) {
        const int rec = 64 + kk * 2 + nf;
        waitv<2>();
        f16x8 B = *(const f16x8*)(ringw + (rec % 3) * 1024 + lane * 16);
        __builtin_amdgcn_s_setprio(1);
        acc2[0][nf] = MFMA16(A0, B, acc2[0][nf]);
        acc2[1][nf] = MFMA16(A1, B, acc2[1][nf]);
        __builtin_amdgcn_s_setprio(0);
        const int nr = rec + 3;
        dma16(wb + (long)nr * 1024 + lane * 16, ringw + (nr % 3) * 1024);
      }
    }
#pragma unroll
    for (int nf = 0; nf < 2; ++nf) {
      int n = wid * 32 + nf * 16 + ln;
      float bias = b2[e * D_H2 + n];
#pragma unroll
      for (int m = 0; m < 2; ++m)
#pragma unroll
        for (int j = 0; j < 4; ++j) {
          float v = acc2[m][nf][j] + bias;
          v = v > 0.f ? v : 0.f;
          int rw = m * 16 + lg * 4 + j;
          *(f16*)(lds + F_H2_OFF + rw * 512 + ((n * 2) ^ ((rw & 15) << 4))) = (f16)v;
        }
    }
  }
  __syncthreads();

  {
    f32x4 acc3[2];
    acc3[0] = (f32x4){0.f, 0.f, 0.f, 0.f};
    acc3[1] = (f32x4){0.f, 0.f, 0.f, 0.f};

#define L3STEP(REC, WAITN)                                                     \
  {                                                                            \
    const int kk3 = (REC) - 96;                                                \
    f16x8 A0 = afragS(lds + F_H2_OFF, 512, 0, kk3 * 64, lane);                 \
    f16x8 A1 = afragS(lds + F_H2_OFF, 512, 16, kk3 * 64, lane);                \
    waitv<WAITN>();                                                            \
    f16x8 B = *(const f16x8*)(ringw + ((REC) % 3) * 1024 + lane * 16);         \
    __builtin_amdgcn_s_setprio(1);                                             \
    acc3[0] = MFMA16(A0, B, acc3[0]);                                          \
    acc3[1] = MFMA16(A1, B, acc3[1]);                                          \
    __builtin_amdgcn_s_setprio(0);                                             \
    if ((REC) + 3 <= 103)                                                      \
      dma16(wb + (long)((REC) + 3) * 1024 + lane * 16,                         \
            ringw + (((REC) + 3) % 3) * 1024);                                 \
  }

    L3STEP(96, 2)
    L3STEP(97, 2)
    L3STEP(98, 2)
    L3STEP(99, 2)
    L3STEP(100, 2)
    L3STEP(101, 2)
    L3STEP(102, 1)
    L3STEP(103, 0)
#undef L3STEP

    int n = wid * 16 + ln;
    float bias = b3[e * D_H3 + n];
#pragma unroll
    for (int m = 0; m < 2; ++m)
#pragma unroll
      for (int j = 0; j < 4; ++j) {
        float v = acc3[m][j] + bias;
        v = v > 0.f ? v : 0.f;
        int rw = m * 16 + lg * 4 + j;
        *(f16*)(lds + rw * 256 + ((n * 2) ^ ((rw & 15) << 4))) = (f16)v;
      }
  }
  __syncthreads();

  if (wid < 2) {
    f32x4 a4 = (f32x4){0.f, 0.f, 0.f, 0.f};
#pragma unroll
    for (int kc = 0; kc < 4; ++kc) {
      f16x8 Bv = *(const f16x8*)(wpe4 + ln * 256 + kc * 64 + lg * 16);
      f16x8 Av = afragS(lds, 256, wid * 16, kc * 64, lane);
      a4 = MFMA16(Av, Bv, a4);
    }
    float bias = b4[e * D_A + ln];
#pragma unroll
    for (int j = 0; j < 4; ++j) {
      float v = a4[j] + bias;
      float mx = v;
      for (int msk = 8; msk >= 1; msk >>= 1) mx = fmaxf(mx, __shfl_xor(mx, msk));
      float pe = expf(v - mx);
      float sm = pe;
      for (int msk = 8; msk >= 1; msk >>= 1) sm += __shfl_xor(sm, msk);
      int rl = wid * 16 + lg * 4 + j;
      if (rl < rvalid) out[(long)idx[row0 + rl] * D_A + ln] = pe / sm;
    }
  }
}

// ---------------- host ----------------

extern "C" void kernel_launch(void* const* d_in, const int* in_sizes, int n_in,
                              void* d_out, int out_size, void* d_ws, size_t ws_size,
                              hipStream_t stream) {
  const float* x  = (const float*)d_in[0];
  const int* pos  = (const int*)d_in[1];
  const float* W1 = (const float*)d_in[2];
  const float* b1 = (const float*)d_in[3];
  const float* W2 = (const float*)d_in[4];
  const float* b2 = (const float*)d_in[5];
  const float* W3 = (const float*)d_in[6];
  const float* b3 = (const float*)d_in[7];
  const float* W4 = (const float*)d_in[8];
  const float* b4 = (const float*)d_in[9];
  float* out = (float*)d_out;

  int* hdr = (int*)d_ws;
  int* idx = hdr + IDX_I;

  hipLaunchKernelGGL(k_bucket, dim3(1), dim3(1024), 0, stream, pos, hdr, idx);

  if (ws_size >= WS_NEED_PIPE) {
    int* sidx = (int*)((char*)d_ws + SIDX_B);
    char* xg = (char*)d_ws + XG_B;
    char* h1 = (char*)d_ws + H1_B;
    char* h2 = (char*)d_ws + H2_B;
    char* h3 = (char*)d_ws + H3_B;
    hipLaunchKernelGGL(k_xcvt, dim3((MP_MAX * 64) / 256), dim3(256), 0, stream,
                       x, hdr, idx, xg, sidx);
    hipLaunchKernelGGL((k_gemm<512, 4>), dim3(MAXT * 4), dim3(512), 0, stream,
                       xg, W1, b1, hdr, h1);
    hipLaunchKernelGGL((k_gemm<512, 2>), dim3(MAXT * 2), dim3(512), 0, stream,
                       h1, W2, b2, hdr, h2);
    hipLaunchKernelGGL((k_gemm<256, 1>), dim3(MAXT), dim3(512), 0, stream,
                       h2, W3, b3, hdr, h3);
    hipLaunchKernelGGL(k_l4, dim3(MAXT), dim3(256), 0, stream,
                       h3, W4, b4, hdr, sidx, out);
  } else {
    char* wp = (char*)d_ws + F_WP_OFF;
    hipLaunchKernelGGL(k_wcvt_f, dim3(F_WSLOTS / 256), dim3(256), 0, stream,
                       W1, W2, W3, W4, wp);
    hipLaunchKernelGGL(k_mlp_f, dim3(F_NTILE), dim3(512), 0, stream,
                       x, b1, b2, b3, b4, hdr, idx, wp, out);
  }
}